// Round 5
// baseline (2886.238 us; speedup 1.0000x reference)
//
#include <hip/hip_runtime.h>
#include <math.h>

#define S_LEN 200
#define BATCH 64
#define HID   512
#define NTAG  22
#define TCH   25              // time-chunk for gates_x staging
#define MC    (TCH*BATCH)     // 1600 rows per chunk GEMM

typedef unsigned short u16;
typedef unsigned int   u32;

__device__ __forceinline__ float bf2f(u16 u){
  union { u32 ui; float f; } v; v.ui = ((u32)u) << 16; return v.f;
}

// ---------------------------------------------------------------------------
__global__ void k_detect(const u32* __restrict__ w, int* __restrict__ flag){
  __shared__ int cnt;
  if (threadIdx.x == 0) cnt = 0;
  __syncthreads();
  int hits = 0;
  for (int i = threadIdx.x; i < 16384; i += 256){
    u32 e = (w[i] & 0x7F80u);
    if (e >= 0x3800u && e <= 0x4080u) hits++;
  }
  atomicAdd(&cnt, hits);
  __syncthreads();
  if (threadIdx.x == 0) *flag = (cnt > 8192) ? 1 : 0;
}

__global__ void k_cvt_f(const void* __restrict__ src, float* __restrict__ dst,
                        int n, const int* __restrict__ flag){
  int i = blockIdx.x*blockDim.x + threadIdx.x;
  if (i >= n) return;
  if (*flag) dst[i] = bf2f(((const u16*)src)[i]);
  else       dst[i] = ((const float*)src)[i];
}

// 4 small tensors in one launch
__global__ void k_cvt4(const void* s0, float* d0, int n0,
                       const void* s1, float* d1, int n1,
                       const void* s2, float* d2, int n2,
                       const void* s3, float* d3, int n3,
                       const int* __restrict__ flag){
  int i = blockIdx.x*blockDim.x + threadIdx.x;
  int isbf = *flag;
  if (i < n0) d0[i] = isbf ? bf2f(((const u16*)s0)[i]) : ((const float*)s0)[i];
  if (i < n1) d1[i] = isbf ? bf2f(((const u16*)s1)[i]) : ((const float*)s1)[i];
  if (i < n2) d2[i] = isbf ? bf2f(((const u16*)s2)[i]) : ((const float*)s2)[i];
  if (i < n3) d3[i] = isbf ? bf2f(((const u16*)s3)[i]) : ((const float*)s3)[i];
}

// whh (both dirs) -> wave-linear swizzle [dir][slice(128)][wave(8)][r(16)][j(64)]
// src row = (r>>2)*512 + slice*4 + (r&3); k = wave*64 + j.
__global__ __launch_bounds__(256)
void k_cvt_whh(const void* __restrict__ wf, const void* __restrict__ wb,
               float* __restrict__ dst, const int* __restrict__ flag){
  int o = blockIdx.x*256 + threadIdx.x;       // 0 .. 2*2048*512-1
  if (o >= 2*2048*512) return;
  int j = o & 63, r = (o>>6)&15, w = (o>>10)&7, slice = (o>>13)&127, dir = o>>20;
  int row = (r>>2)*512 + slice*4 + (r&3);
  int si = row*512 + w*64 + j;
  const void* src = dir ? wb : wf;
  float v = (*flag) ? bf2f(((const u16*)src)[si]) : ((const float*)src)[si];
  dst[o] = v;
}

// W_out [1024][22] -> wpad [2][512][24]  (tag-padded, k-major per half)
__global__ void k_cvt_wt(const void* __restrict__ src, float* __restrict__ dst,
                         const int* __restrict__ flag){
  int i = blockIdx.x*blockDim.x + threadIdx.x;   // over 1024*24
  if (i >= 1024*24) return;
  int k = i / 24, tag = i % 24;
  float v = 0.f;
  if (tag < NTAG){
    v = (*flag) ? bf2f(((const u16*)src)[k*NTAG + tag])
                : ((const float*)src)[k*NTAG + tag];
  }
  int half = k >> 9, kk = k & 511;
  dst[((size_t)half*512 + kk)*24 + tag] = v;
}

__global__ void k_zero(float* __restrict__ p, int n){
  int i = blockIdx.x*blockDim.x + threadIdx.x;
  if (i < n) p[i] = 0.f;
}

// ---------------------------------------------------------------------------
// Build fwd_in/bwd_in [S][B][256] fp32.
__global__ __launch_bounds__(128)
void k_build(const int* __restrict__ ci, const int* __restrict__ lengths,
             const int* __restrict__ gid, const int* __restrict__ gm,
             const int* __restrict__ rgid, const int* __restrict__ rgm,
             const void* __restrict__ ctab, const void* __restrict__ gtab,
             const int* __restrict__ flag,
             float* __restrict__ fin, float* __restrict__ bin)
{
  int bs = blockIdx.x;              // b*S_LEN + s
  int b = bs / S_LEN, s = bs % S_LEN;
  int d = threadIdx.x;              // 0..127
  int isbf = *flag;
  int len = lengths[b];
  int sb = (s < len) ? (len - 1 - s) : s;
  size_t orow = ((size_t)s*BATCH + b)*256;

  {
    int cid = ci[bs];
    float cv = isbf ? bf2f(((const u16*)ctab)[(size_t)cid*128 + d])
                    : ((const float*)ctab)[(size_t)cid*128 + d];
    fin[orow + d] = cv;
    const int* gg = gid + (size_t)bs*8;
    const int* mm = gm  + (size_t)bs*8;
    float sum = 0.f, cntf = 0.f;
    for (int g = 0; g < 8; ++g){
      float m = (float)mm[g];
      int gw = gg[g];
      float gv = isbf ? bf2f(((const u16*)gtab)[(size_t)gw*128 + d])
                      : ((const float*)gtab)[(size_t)gw*128 + d];
      sum += m * gv; cntf += m;
    }
    fin[orow + 128 + d] = sum / fmaxf(cntf, 1.f);
  }
  {
    int bsr = b*S_LEN + sb;
    int cid = ci[bsr];
    float cv = isbf ? bf2f(((const u16*)ctab)[(size_t)cid*128 + d])
                    : ((const float*)ctab)[(size_t)cid*128 + d];
    bin[orow + d] = cv;
    const int* gg = rgid + (size_t)bsr*8;
    const int* mm = rgm  + (size_t)bsr*8;
    float sum = 0.f, cntf = 0.f;
    for (int g = 0; g < 8; ++g){
      float m = (float)mm[g];
      int gw = gg[g];
      float gv = isbf ? bf2f(((const u16*)gtab)[(size_t)gw*128 + d])
                      : ((const float*)gtab)[(size_t)gw*128 + d];
      sum += m * gv; cntf += m;
    }
    bin[orow + 128 + d] = sum / fmaxf(cntf, 1.f);
  }
}

// ---------------------------------------------------------------------------
// Chunked gates_x GEMM v2: 64x128 tile, 8x4 micro-tile.
// C[dir][n][m] = A.W^T + bias (transposed store), m in chunk-local rows.
__global__ __launch_bounds__(256)
void k_gemm_ih(const float* __restrict__ Af, const float* __restrict__ Ab,
               const float* __restrict__ wih,   // [2][2048][256]
               const float* __restrict__ bias,  // [2][2048]
               float* __restrict__ gxc,         // [2][2048][MC]
               int t0)
{
  const int dir = blockIdx.z;
  const float* A = (dir ? Ab : Af) + (size_t)t0*BATCH*256;
  const float* W = wih + (size_t)dir*2048*256;
  const float* bi = bias + (size_t)dir*2048;
  float* C = gxc + (size_t)dir*2048*MC;
  const int m0 = blockIdx.y * 64;     // 25 blocks
  const int n0 = blockIdx.x * 128;    // 16 blocks
  const int tid = threadIdx.x;
  __shared__ float As[32][64];
  __shared__ float Ws[32][128];
  const int lrA = tid >> 2, kqA = (tid & 3)*8;
  const int lrW = tid >> 1, kqW = (tid & 1)*16;
  const int tx = tid & 31, ty = tid >> 5;     // cols tx*4, rows ty*8
  float acc[8][4] = {};

  for (int k0 = 0; k0 < 256; k0 += 32){
    float4 a0 = *(const float4*)(A + (size_t)(m0+lrA)*256 + k0+kqA);
    float4 a1 = *(const float4*)(A + (size_t)(m0+lrA)*256 + k0+kqA+4);
    float4 w0 = *(const float4*)(W + (size_t)(n0+lrW)*256 + k0+kqW);
    float4 w1 = *(const float4*)(W + (size_t)(n0+lrW)*256 + k0+kqW+4);
    float4 w2 = *(const float4*)(W + (size_t)(n0+lrW)*256 + k0+kqW+8);
    float4 w3 = *(const float4*)(W + (size_t)(n0+lrW)*256 + k0+kqW+12);
    As[kqA+0][lrA]=a0.x; As[kqA+1][lrA]=a0.y; As[kqA+2][lrA]=a0.z; As[kqA+3][lrA]=a0.w;
    As[kqA+4][lrA]=a1.x; As[kqA+5][lrA]=a1.y; As[kqA+6][lrA]=a1.z; As[kqA+7][lrA]=a1.w;
    Ws[kqW+ 0][lrW]=w0.x; Ws[kqW+ 1][lrW]=w0.y; Ws[kqW+ 2][lrW]=w0.z; Ws[kqW+ 3][lrW]=w0.w;
    Ws[kqW+ 4][lrW]=w1.x; Ws[kqW+ 5][lrW]=w1.y; Ws[kqW+ 6][lrW]=w1.z; Ws[kqW+ 7][lrW]=w1.w;
    Ws[kqW+ 8][lrW]=w2.x; Ws[kqW+ 9][lrW]=w2.y; Ws[kqW+10][lrW]=w2.z; Ws[kqW+11][lrW]=w2.w;
    Ws[kqW+12][lrW]=w3.x; Ws[kqW+13][lrW]=w3.y; Ws[kqW+14][lrW]=w3.z; Ws[kqW+15][lrW]=w3.w;
    __syncthreads();
    #pragma unroll 8
    for (int kk = 0; kk < 32; ++kk){
      float4 av0 = *(const float4*)(&As[kk][ty*8]);
      float4 av1 = *(const float4*)(&As[kk][ty*8+4]);
      float4 wv  = *(const float4*)(&Ws[kk][tx*4]);
      acc[0][0]+=av0.x*wv.x; acc[0][1]+=av0.x*wv.y; acc[0][2]+=av0.x*wv.z; acc[0][3]+=av0.x*wv.w;
      acc[1][0]+=av0.y*wv.x; acc[1][1]+=av0.y*wv.y; acc[1][2]+=av0.y*wv.z; acc[1][3]+=av0.y*wv.w;
      acc[2][0]+=av0.z*wv.x; acc[2][1]+=av0.z*wv.y; acc[2][2]+=av0.z*wv.z; acc[2][3]+=av0.z*wv.w;
      acc[3][0]+=av0.w*wv.x; acc[3][1]+=av0.w*wv.y; acc[3][2]+=av0.w*wv.z; acc[3][3]+=av0.w*wv.w;
      acc[4][0]+=av1.x*wv.x; acc[4][1]+=av1.x*wv.y; acc[4][2]+=av1.x*wv.z; acc[4][3]+=av1.x*wv.w;
      acc[5][0]+=av1.y*wv.x; acc[5][1]+=av1.y*wv.y; acc[5][2]+=av1.y*wv.z; acc[5][3]+=av1.y*wv.w;
      acc[6][0]+=av1.z*wv.x; acc[6][1]+=av1.z*wv.y; acc[6][2]+=av1.z*wv.z; acc[6][3]+=av1.z*wv.w;
      acc[7][0]+=av1.w*wv.x; acc[7][1]+=av1.w*wv.y; acc[7][2]+=av1.w*wv.z; acc[7][3]+=av1.w*wv.w;
    }
    __syncthreads();
  }

  #pragma unroll
  for (int jn = 0; jn < 4; ++jn){
    int col = n0 + tx*4 + jn;
    float bj = bi[col];
    float4 o0 = make_float4(acc[0][jn]+bj, acc[1][jn]+bj, acc[2][jn]+bj, acc[3][jn]+bj);
    float4 o1 = make_float4(acc[4][jn]+bj, acc[5][jn]+bj, acc[6][jn]+bj, acc[7][jn]+bj);
    *(float4*)(C + (size_t)col*MC + m0 + ty*8)     = o0;
    *(float4*)(C + (size_t)col*MC + m0 + ty*8 + 4) = o1;
  }
}

// ---------------------------------------------------------------------------
// LSTM step v4: weights from wave-linear swizzled table (contiguous 4KB of
// provably-uniform addresses per wave -> s_load); gx/c prefetched to regs
// before the dot product; h as coalesced vector loads.
__global__ __launch_bounds__(512)
void k_step(const float* __restrict__ wsw,    // [2][128][8][16][64]
            const float* __restrict__ gxc,    // [2][2048][MC]
            float* __restrict__ hbuf,         // [2][2][512][64]
            float* __restrict__ cbuf,         // [2][512][64]
            float* __restrict__ hseq,         // [2][200][512][64]
            int t, int tc)
{
  const int dir = blockIdx.y;
  const int slice = blockIdx.x;        // 0..127
  const int hrow_base = slice*4;
  const int tid = threadIdx.x;
  const int b = tid & 63;
  const int uw = __builtin_amdgcn_readfirstlane(tid >> 6);  // wave 0..7
  const int uk0 = uw * 64;

  __shared__ float part[8*16*64];      // 32 KB

  const float* hprev = hbuf + (size_t)(dir*2 + (t&1))*HID*BATCH;
  float* hnext       = hbuf + (size_t)(dir*2 + ((t+1)&1))*HID*BATCH;

  // prefetch epilogue operands (independent of h)
  float pgi=0.f, pgf=0.f, pgg=0.f, pgo=0.f, pc=0.f;
  if (tid < 256){
    const int hr = tid >> 6, bb = tid & 63;
    const int hrow = hrow_base + hr;
    const float* gxb = gxc + (size_t)dir*2048*MC + (size_t)tc*BATCH + bb;
    pgi = gxb[(size_t)(   0 + hrow)*MC];
    pgf = gxb[(size_t)( 512 + hrow)*MC];
    pgg = gxb[(size_t)(1024 + hrow)*MC];
    pgo = gxb[(size_t)(1536 + hrow)*MC];
    pc  = cbuf[((size_t)dir*HID + hrow)*BATCH + bb];
  }

  // this wave's h slice -> registers (coalesced vector loads)
  float hv[64];
  #pragma unroll
  for (int j = 0; j < 64; ++j)
    hv[j] = hprev[(size_t)(uk0 + j)*BATCH + b];

  // wave-linear weight base: contiguous 1024 floats, fully uniform
  const float* wv_base = wsw + (((size_t)(dir*128 + slice))*8 + uw)*1024;

  float acc[16];
  #pragma unroll
  for (int r = 0; r < 16; ++r) acc[r] = 0.f;

  #pragma unroll
  for (int r = 0; r < 16; ++r){
    const float* wr = wv_base + r*64;
    #pragma unroll
    for (int j = 0; j < 64; ++j)
      acc[r] += wr[j] * hv[j];
  }

  #pragma unroll
  for (int r = 0; r < 16; ++r)
    part[(uw*16 + r)*64 + b] = acc[r];
  __syncthreads();

  if (tid < 256){
    const int hr = tid >> 6;
    const int bb = tid & 63;
    const int hrow = hrow_base + hr;
    float g4[4];
    #pragma unroll
    for (int g = 0; g < 4; ++g){
      const int r = g*4 + hr;
      float s = 0.f;
      #pragma unroll
      for (int ww = 0; ww < 8; ++ww)
        s += part[(ww*16 + r)*64 + bb];
      g4[g] = s;
    }
    float gi = g4[0] + pgi;
    float gf = g4[1] + pgf;
    float gg = g4[2] + pgg;
    float go = g4[3] + pgo;
    float si = 1.f/(1.f+expf(-gi));
    float sf = 1.f/(1.f+expf(-gf));
    float so = 1.f/(1.f+expf(-go));
    float c = sf*pc + si*tanhf(gg);
    float h = so*tanhf(c);
    cbuf[((size_t)dir*HID + hrow)*BATCH + bb] = c;
    hnext[(size_t)hrow*BATCH + bb] = h;
    hseq[(((size_t)dir*S_LEN + t)*HID + hrow)*BATCH + bb] = h;
  }
}

// ---------------------------------------------------------------------------
// Emissions: grid (S_LEN, 2), 256 threads; h through LDS; weights scalar.
__global__ __launch_bounds__(256)
void k_emis(const float* __restrict__ hseq, const int* __restrict__ lengths,
            const float* __restrict__ wpad,   // [2][512][24]
            const float* __restrict__ bout,   // [22]
            float* __restrict__ emisF, float* __restrict__ emisB)
{
  const int t = blockIdx.x;
  const int dir = blockIdx.y;
  const int tid = threadIdx.x;
  const int b = tid & 63;
  const int utg = __builtin_amdgcn_readfirstlane(tid >> 6);  // 0..3

  __shared__ float hl[64*64];          // 16 KB

  const float* hsrc = hseq + ((size_t)(dir*S_LEN + t)*HID)*BATCH;
  const float* wbase = wpad + (size_t)dir*512*24 + utg*6;

  float acc[6] = {0.f,0.f,0.f,0.f,0.f,0.f};

  for (int c = 0; c < 8; ++c){
    const float4* s4 = (const float4*)(hsrc + (size_t)c*64*64);
    float4* d4 = (float4*)hl;
    #pragma unroll
    for (int q = 0; q < 4; ++q) d4[q*256 + tid] = s4[q*256 + tid];
    __syncthreads();
    const float* wrow = wbase + (size_t)c*64*24;
    #pragma unroll 4
    for (int k = 0; k < 64; ++k){
      float hval = hl[k*64 + b];
      #pragma unroll
      for (int i = 0; i < 6; ++i) acc[i] += hval * wrow[k*24 + i];
    }
    __syncthreads();
  }

  const int len = lengths[b];
  const int pos = dir ? ((t < len) ? (len - 1 - t) : t) : t;
  float* dst = (dir ? emisB : emisF) + ((size_t)b*S_LEN + pos)*NTAG;
  #pragma unroll
  for (int i = 0; i < 6; ++i){
    int tag = utg*6 + i;
    if (tag < NTAG) dst[tag] = acc[i] + (dir ? 0.f : bout[tag]);
  }
}

// ---------------------------------------------------------------------------
// Viterbi v2: one wave per batch; transitions-column + part in registers,
// shfl broadcast, no barriers in hot loop; emission prefetch.
__global__ __launch_bounds__(64)
void k_viterbi(const float* __restrict__ emisF, const float* __restrict__ emisB,
               const int* __restrict__ lengths,
               const float* __restrict__ trans, int* __restrict__ out)
{
  const int b = blockIdx.x;
  const int j = threadIdx.x;
  __shared__ unsigned char bp[(S_LEN-1)*NTAG];
  const int len = lengths[b];
  const float* ef = emisF + (size_t)b*S_LEN*NTAG;
  const float* eb = emisB + (size_t)b*S_LEN*NTAG;
  const bool act = (j < NTAG);

  float trc[NTAG];
  #pragma unroll
  for (int i = 0; i < NTAG; ++i)
    trc[i] = act ? trans[i*NTAG + j] : 0.f;
  const float trstop = act ? trans[j*NTAG + (NTAG-1)] : 0.f;

  float part = act ? (ef[j] + eb[j] + trans[(NTAG-2)*NTAG + j]) : -3.4e38f;
  float e_next = act ? (ef[NTAG + j] + eb[NTAG + j]) : 0.f;

  for (int t = 1; t < S_LEN; ++t){
    float e = e_next;
    if (t+1 < S_LEN && act) e_next = ef[(t+1)*NTAG + j] + eb[(t+1)*NTAG + j];
    float best = -3.4e38f; int bi = 0;
    #pragma unroll
    for (int i = 0; i < NTAG; ++i){
      float v = __shfl(part, i) + trc[i];
      if (v > best){ best = v; bi = i; }      // first-max (jnp.argmax)
    }
    if (t < len) part = best + e;
    if (act) bp[(t-1)*NTAG + j] = (unsigned char)((t < len) ? bi : j);
  }

  float fin = part + trstop;
  float best = -3.4e38f; int tag = 0;
  #pragma unroll
  for (int i = 0; i < NTAG; ++i){
    float v = __shfl(fin, i);
    if (v > best){ best = v; tag = i; }
  }
  __builtin_amdgcn_wave_barrier();
  if (j == 0){
    out[b*S_LEN + S_LEN-1] = (S_LEN-1 < len) ? tag : 0;
    for (int t = S_LEN-2; t >= 0; --t){
      tag = bp[t*NTAG + tag];
      out[b*S_LEN + t] = (t < len) ? tag : 0;
    }
  }
}

// ---------------------------------------------------------------------------
extern "C" void kernel_launch(void* const* d_in, const int* in_sizes, int n_in,
                              void* d_out, int out_size, void* d_ws, size_t ws_size,
                              hipStream_t stream)
{
  (void)in_sizes; (void)n_in; (void)out_size; (void)ws_size;
  const int* char_inputs  = (const int*)d_in[0];
  const int* lengths      = (const int*)d_in[1];
  const int* gaz_ids      = (const int*)d_in[3];
  const int* gaz_mask     = (const int*)d_in[4];
  const int* rev_gaz_ids  = (const int*)d_in[5];
  const int* rev_gaz_mask = (const int*)d_in[6];
  const void* char_table  = d_in[7];
  const void* gaz_table   = d_in[8];
  const void* w_ih_f = d_in[9];
  const void* w_hh_f = d_in[10];
  const void* b_f    = d_in[11];
  const void* w_ih_b = d_in[12];
  const void* w_hh_b = d_in[13];
  const void* b_b    = d_in[14];
  const void* W_out  = d_in[15];
  const void* b_out  = d_in[16];
  const void* trans  = d_in[17];

  char* ws = (char*)d_ws;
  size_t off = 0;
  auto alloc = [&](size_t bytes)->char*{
    char* p = ws + off; off = (off + bytes + 255) & ~(size_t)255; return p;
  };
  int*   flag   = (int*)  alloc(256);
  float* wsw    = (float*)alloc(2ull*2048*512*4);   //  8.4 MB (swizzled whh)
  float* wih32  = (float*)alloc(2ull*2048*256*4);   //  4.2 MB
  float* bias32 = (float*)alloc(2ull*2048*4);
  float* wpad   = (float*)alloc(2ull*512*24*4);
  float* bout32 = (float*)alloc(22ull*4);
  float* trans32= (float*)alloc(484ull*4);
  float* fwd_in = (float*)alloc(12800ull*256*4);    // 13.1 MB
  float* bwd_in = (float*)alloc(12800ull*256*4);    // 13.1 MB
  float* gxc    = (float*)alloc(2ull*2048*MC*4);    // 26.2 MB
  float* hbuf   = (float*)alloc(2ull*2*512*64*4);
  float* cbuf   = (float*)alloc(2ull*512*64*4);
  float* hseq   = (float*)alloc(2ull*200*512*64*4); // 52.4 MB
  float* emisF  = (float*)alloc(12800ull*22*4);
  float* emisB  = (float*)alloc(12800ull*22*4);

  k_detect<<<1,256,0,stream>>>((const u32*)char_table, flag);
  k_cvt_whh<<<8192,256,0,stream>>>(w_hh_f, w_hh_b, wsw, flag);
  k_cvt_f<<<2048,256,0,stream>>>(w_ih_f, wih32,          524288, flag);
  k_cvt_f<<<2048,256,0,stream>>>(w_ih_b, wih32 + 524288, 524288, flag);
  k_cvt4<<<8,256,0,stream>>>(b_f, bias32, 2048,
                             b_b, bias32 + 2048, 2048,
                             b_out, bout32, 22,
                             trans, trans32, 484, flag);
  k_cvt_wt<<<96,256,0,stream>>>(W_out, wpad, flag);

  k_build<<<12800,128,0,stream>>>(char_inputs, lengths, gaz_ids, gaz_mask,
                                  rev_gaz_ids, rev_gaz_mask, char_table, gaz_table,
                                  flag, fwd_in, bwd_in);

  k_zero<<<768,256,0,stream>>>(hbuf, 2*2*512*64 + 2*512*64);

  for (int t0 = 0; t0 < S_LEN; t0 += TCH){
    k_gemm_ih<<<dim3(16,TCH,2),256,0,stream>>>(fwd_in, bwd_in, wih32, bias32,
                                               gxc, t0);
    for (int tc = 0; tc < TCH; ++tc)
      k_step<<<dim3(128,2),512,0,stream>>>(wsw, gxc, hbuf, cbuf, hseq, t0+tc, tc);
  }

  k_emis<<<dim3(S_LEN,2),256,0,stream>>>(hseq, lengths, wpad, bout32, emisF, emisB);
  k_viterbi<<<64,64,0,stream>>>(emisF, emisB, lengths, trans32, (int*)d_out);
}